// Round 1
// baseline (256.086 us; speedup 1.0000x reference)
//
#include <hip/hip_runtime.h>
#include <math.h>

#define BB 64
#define TT 577
#define DD 768
#define DENS 519   // int(577*0.9)
#define NSKIP 58

// ---------------------------------------------------------------------------
// Kernel 1: prob[b,t] = sigmoid(dot(x[b,t,:], w) + bias), fp64 accumulate.
// One wave (64 lanes) per row; float4 coalesced loads (3 per lane).
// ---------------------------------------------------------------------------
__global__ __launch_bounds__(256) void k_prob(const float* __restrict__ x,
                                              const float* __restrict__ w,
                                              const float* __restrict__ bias,
                                              double* __restrict__ prob,
                                              int nrows) {
    int wave = (int)((blockIdx.x * blockDim.x + threadIdx.x) >> 6);
    int lane = threadIdx.x & 63;
    if (wave >= nrows) return;
    const float4* r4 = (const float4*)(x + (size_t)wave * DD);
    const float4* w4 = (const float4*)w;
    double acc = 0.0;
#pragma unroll
    for (int i = 0; i < 3; ++i) {
        float4 a = r4[lane + 64 * i];
        float4 b = w4[lane + 64 * i];
        acc += (double)a.x * (double)b.x + (double)a.y * (double)b.y
             + (double)a.z * (double)b.z + (double)a.w * (double)b.w;
    }
#pragma unroll
    for (int off = 32; off; off >>= 1)
        acc += __shfl_down(acc, off, 64);
    if (lane == 0) {
        double z = acc + (double)bias[0];
        prob[wave] = 1.0 / (1.0 + exp(-z));
    }
}

// ---------------------------------------------------------------------------
// Kernel 2: per-batch stable ranking + softmax weights.
// r_desc(i) = #{j: p[j]>p[i]} + #{j<i: p[j]==p[i]}  (jax top_k order, desc)
// r_asc(i)  = #{j: p[j]<p[i]} + #{j<i: p[j]==p[i]}  (jax top_k of -p order)
// ---------------------------------------------------------------------------
__global__ __launch_bounds__(640) void k_rank(const double* __restrict__ prob,
                                              int* __restrict__ tok_src,
                                              int* __restrict__ skip_src,
                                              float* __restrict__ skip_w) {
    __shared__ double p[TT];
    __shared__ double sp[NSKIP];
    int b = blockIdx.x;
    int i = threadIdx.x;
    if (i < TT) p[i] = prob[b * TT + i];
    __syncthreads();
    if (i < TT) {
        double pi = p[i];
        int r_desc = 0, r_asc = 0;
        for (int j = 0; j < TT; ++j) {
            double pj = p[j];
            bool tie = (pj == pi) & (j < i);
            r_desc += ((pj > pi) | tie) ? 1 : 0;
            r_asc  += ((pj < pi) | tie) ? 1 : 0;
        }
        if (r_desc < DENS)  tok_src[b * DENS + r_desc] = i;
        if (r_asc < NSKIP) { skip_src[b * NSKIP + r_asc] = i; sp[r_asc] = pi; }
    }
    __syncthreads();
    // softmax over the 58 skipped probs (ascending order) — first wave only
    if (i < 64) {
        double v = (i < NSKIP) ? sp[i] : -1.0e300;
        double m = v;
#pragma unroll
        for (int off = 32; off; off >>= 1) {
            double o = __shfl_down(m, off, 64);
            m = (o > m) ? o : m;
        }
        m = __shfl(m, 0, 64);
        double e = (i < NSKIP) ? exp(v - m) : 0.0;
        double s = e;
#pragma unroll
        for (int off = 32; off; off >>= 1)
            s += __shfl_down(s, off, 64);
        s = __shfl(s, 0, 64);
        if (i < NSKIP) skip_w[b * NSKIP + i] = (float)(e / s);
    }
}

// ---------------------------------------------------------------------------
// Kernel 3: gather rows. One wave per output row (tokens then skip_tokens).
// ---------------------------------------------------------------------------
__global__ __launch_bounds__(256) void k_gather(const float* __restrict__ x,
                                                const int* __restrict__ tok_src,
                                                const int* __restrict__ skip_src,
                                                float* __restrict__ out) {
    int wave = (int)((blockIdx.x * blockDim.x + threadIdx.x) >> 6);
    int lane = threadIdx.x & 63;
    if (wave >= BB * TT) return;
    int b = wave / TT;
    int k = wave - b * TT;
    int src;
    size_t dst;
    if (k < DENS) {
        src = tok_src[b * DENS + k];
        dst = (size_t)(b * DENS + k) * DD;
    } else {
        int k2 = k - DENS;
        src = skip_src[b * NSKIP + k2];
        dst = (size_t)BB * DENS * DD + (size_t)(b * NSKIP + k2) * DD;
    }
    const float4* s4 = (const float4*)(x + ((size_t)b * TT + src) * DD);
    float4* d4 = (float4*)(out + dst);
#pragma unroll
    for (int i = 0; i < 3; ++i)
        d4[lane + 64 * i] = s4[lane + 64 * i];
}

// ---------------------------------------------------------------------------
// Kernel 4: summary[b,d] = sum_k w[b,k] * skip_tokens[b,k,d]
// One block per batch; 256 threads × 3 columns each.
// ---------------------------------------------------------------------------
__global__ __launch_bounds__(256) void k_summary(const float* __restrict__ skip_tok,
                                                 const float* __restrict__ skip_w,
                                                 float* __restrict__ summary) {
    int b = blockIdx.x;
    int t = threadIdx.x;
    float a0 = 0.f, a1 = 0.f, a2 = 0.f;
    for (int k = 0; k < NSKIP; ++k) {
        float wk = skip_w[b * NSKIP + k];
        const float* row = skip_tok + (size_t)(b * NSKIP + k) * DD;
        a0 += wk * row[t];
        a1 += wk * row[t + 256];
        a2 += wk * row[t + 512];
    }
    summary[b * DD + t]       = a0;
    summary[b * DD + t + 256] = a1;
    summary[b * DD + t + 512] = a2;
}

extern "C" void kernel_launch(void* const* d_in, const int* in_sizes, int n_in,
                              void* d_out, int out_size, void* d_ws, size_t ws_size,
                              hipStream_t stream) {
    const float* x    = (const float*)d_in[0];
    const float* w    = (const float*)d_in[1];
    const float* bias = (const float*)d_in[2];
    float* out = (float*)d_out;
    char* ws = (char*)d_ws;

    const int nrows = BB * TT;                   // 36928
    double* prob   = (double*)ws;                                    // 36928*8 = 295424 B
    int* tok_src   = (int*)(ws + 295424);                            // 64*519*4 = 132864 B
    int* skip_src  = (int*)(ws + 295424 + 132864);                   // 64*58*4  = 14848 B
    float* skip_w  = (float*)(ws + 295424 + 132864 + 14848);         // 64*58*4  = 14848 B

    k_prob<<<nrows / 4, 256, 0, stream>>>(x, w, bias, prob, nrows);
    k_rank<<<BB, 640, 0, stream>>>(prob, tok_src, skip_src, skip_w);
    k_gather<<<nrows / 4, 256, 0, stream>>>(x, tok_src, skip_src, out);

    float* skip_tok = out + (size_t)BB * DENS * DD;
    float* summary  = out + (size_t)BB * (DENS + NSKIP) * DD;
    k_summary<<<BB, 256, 0, stream>>>(skip_tok, skip_w, summary);
}